// Round 5
// baseline (374.092 us; speedup 1.0000x reference)
//
#include <hip/hip_runtime.h>
#include <math.h>

#define BN 16
#define DN 2048
#define ADA 1024
#define INTER 1024
#define NW2 32768   // D*RANK*2
#define HALFN 16384

// ===========================================================================
// xwinit: xw[m][n] = b2[n]  (atomic accumulator pre-init)
__global__ void xwinit(const float* __restrict__ b2, float* __restrict__ xw) {
    const int i = blockIdx.x * 256 + threadIdx.x;   // float4 idx over 131072
    ((float4*)xw)[i] = ((const float4*)b2)[i & (NW2 / 4 - 1)];
}

// ===========================================================================
// K1a2: h_pre[m][j] += sum_{k in 32-chunk} ada[m][k] * w1[k][j]
// grid 32 (k-split), block 256 (thread owns float4 of j, all 1024 cols).
// ada chunk staged to LDS [kk][m]; w1 float4 stream, 8-deep rolling prefetch.
__global__ __launch_bounds__(256) void k1a2(const float* __restrict__ ada,
                                            const float* __restrict__ w1,
                                            float* __restrict__ h_pre) {
    const int t  = threadIdx.x;
    const int k0 = blockIdx.x * 32;
    __shared__ float al[32][16];
    for (int i = t; i < 512; i += 256)
        al[i >> 4][i & 15] = ada[(i & 15) * ADA + k0 + (i >> 4)];
    __syncthreads();

    float4 acc[16];
#pragma unroll
    for (int m = 0; m < 16; ++m) acc[m] = make_float4(0.f, 0.f, 0.f, 0.f);

    const float4* wp = (const float4*)w1 + (size_t)k0 * (INTER / 4) + t;
    float4 wbuf[8];
#pragma unroll
    for (int u = 0; u < 8; ++u) wbuf[u] = wp[(size_t)u * (INTER / 4)];

    for (int ko = 0; ko < 4; ++ko) {
#pragma unroll
        for (int u = 0; u < 8; ++u) {
            const int kk = ko * 8 + u;
            const float4 wv = wbuf[u];
            const int nk = (kk + 8 < 32) ? kk + 8 : kk;   // uniform clamp
            wbuf[u] = wp[(size_t)nk * (INTER / 4)];
            const float4 h0 = *(const float4*)&al[kk][0];
            const float4 h1 = *(const float4*)&al[kk][4];
            const float4 h2 = *(const float4*)&al[kk][8];
            const float4 h3 = *(const float4*)&al[kk][12];
#define A1(m, hs) do { acc[m].x = fmaf(hs, wv.x, acc[m].x); \
                       acc[m].y = fmaf(hs, wv.y, acc[m].y); \
                       acc[m].z = fmaf(hs, wv.z, acc[m].z); \
                       acc[m].w = fmaf(hs, wv.w, acc[m].w); } while (0)
            A1(0, h0.x);  A1(1, h0.y);  A1(2, h0.z);  A1(3, h0.w);
            A1(4, h1.x);  A1(5, h1.y);  A1(6, h1.z);  A1(7, h1.w);
            A1(8, h2.x);  A1(9, h2.y);  A1(10, h2.z); A1(11, h2.w);
            A1(12, h3.x); A1(13, h3.y); A1(14, h3.z); A1(15, h3.w);
#undef A1
        }
    }
#pragma unroll
    for (int m = 0; m < 16; ++m) {
        float* d = h_pre + m * INTER + t * 4;
        atomicAdd(d + 0, acc[m].x); atomicAdd(d + 1, acc[m].y);
        atomicAdd(d + 2, acc[m].z); atomicAdd(d + 3, acc[m].w);
    }
}

// ===========================================================================
// K1bt: h_t[k][m] = gelu_exact(h_pre[m][k] + b1[k])
__global__ void k1bt(const float* __restrict__ h_pre, const float* __restrict__ b1,
                     float* __restrict__ h_t) {
    int i = blockIdx.x * 256 + threadIdx.x;     // 16384, i = m*1024 + k
    int m = i >> 10, k = i & (INTER - 1);
    float v = h_pre[i] + b1[k];
    float g = 0.5f * v * (1.f + erff(v * 0.70710678118654752f));
    h_t[k * BN + m] = g;
}

// ===========================================================================
// K2s: xw[m][n] += sum_{k in 32-chunk} h_t[k][m] * w2[k][n]   (atomic)
// grid (32 n-tiles, 32 k-split), block 256. Thread owns float4 of n (n-tile
// 1024 floats = one 4 KB page per k-row). h chunk in LDS (lgkmcnt path only);
// w2 is the sole vmcnt stream: float4, 8-deep rolling prefetch, no barriers.
__global__ __launch_bounds__(256) void k2s(const float* __restrict__ h_t,
                                           const float* __restrict__ w2,
                                           float* __restrict__ xw) {
    const int t  = threadIdx.x;
    const int n4 = blockIdx.x * 256 + t;            // float4 col [0, 8192)
    const int k0 = blockIdx.y * 32;
    __shared__ float hl[32][16];
    if (t < 128) ((float4*)hl)[t] = ((const float4*)(h_t + k0 * BN))[t];
    __syncthreads();

    float4 acc[16];
#pragma unroll
    for (int m = 0; m < 16; ++m) acc[m] = make_float4(0.f, 0.f, 0.f, 0.f);

    const float4* wp = (const float4*)w2 + (size_t)k0 * (NW2 / 4) + n4;
    float4 wbuf[8];
#pragma unroll
    for (int u = 0; u < 8; ++u) wbuf[u] = wp[(size_t)u * (NW2 / 4)];

    for (int ko = 0; ko < 4; ++ko) {
#pragma unroll
        for (int u = 0; u < 8; ++u) {
            const int kk = ko * 8 + u;
            const float4 wv = wbuf[u];
            const int nk = (kk + 8 < 32) ? kk + 8 : kk;   // uniform clamp
            wbuf[u] = wp[(size_t)nk * (NW2 / 4)];
            const float4 h0 = *(const float4*)&hl[kk][0];
            const float4 h1 = *(const float4*)&hl[kk][4];
            const float4 h2 = *(const float4*)&hl[kk][8];
            const float4 h3 = *(const float4*)&hl[kk][12];
#define A2(m, hs) do { acc[m].x = fmaf(hs, wv.x, acc[m].x); \
                       acc[m].y = fmaf(hs, wv.y, acc[m].y); \
                       acc[m].z = fmaf(hs, wv.z, acc[m].z); \
                       acc[m].w = fmaf(hs, wv.w, acc[m].w); } while (0)
            A2(0, h0.x);  A2(1, h0.y);  A2(2, h0.z);  A2(3, h0.w);
            A2(4, h1.x);  A2(5, h1.y);  A2(6, h1.z);  A2(7, h1.w);
            A2(8, h2.x);  A2(9, h2.y);  A2(10, h2.z); A2(11, h2.w);
            A2(12, h3.x); A2(13, h3.y); A2(14, h3.z); A2(15, h3.w);
#undef A2
        }
    }
#pragma unroll
    for (int m = 0; m < 16; ++m) {
        float* d = xw + (size_t)m * NW2 + n4 * 4;
        atomicAdd(d + 0, acc[m].x); atomicAdd(d + 1, acc[m].y);
        atomicAdd(d + 2, acc[m].z); atomicAdd(d + 3, acc[m].w);
    }
}

// ===========================================================================
// K3: t[m][r] = sum_c x[m][c] * xw[m][c*8+r]   (x_a half)
__global__ void k3(const float* __restrict__ x, const float* __restrict__ xw,
                   float* __restrict__ t) {
    const int m = blockIdx.x >> 3, r = blockIdx.x & 7;
    float s = 0.f;
    for (int c = threadIdx.x; c < DN; c += 256)
        s += x[m * DN + c] * xw[(size_t)m * NW2 + c * 8 + r];
    __shared__ float red[256];
    red[threadIdx.x] = s;
    __syncthreads();
    for (int off = 128; off > 0; off >>= 1) {
        if (threadIdx.x < off) red[threadIdx.x] += red[threadIdx.x + off];
        __syncthreads();
    }
    if (threadIdx.x == 0) t[m * 8 + r] = red[0];
}

// ===========================================================================
// K5i: out[m][o] = x[m][o] + sum_r t[m][r] * x_b[m][o][r]   (pre-init for k4a)
__global__ void k5i(const float* __restrict__ x, const float* __restrict__ xw,
                    const float* __restrict__ t, float* __restrict__ out) {
    const int i = blockIdx.x * 256 + threadIdx.x;   // [0, 32768)
    const int m = i >> 11, o = i & (DN - 1);
    const float4 xb0 = *(const float4*)(xw + (size_t)m * NW2 + HALFN + o * 8);
    const float4 xb1 = *(const float4*)(xw + (size_t)m * NW2 + HALFN + o * 8 + 4);
    const float* tm = t + m * 8;
    out[i] = x[i]
           + tm[0] * xb0.x + tm[1] * xb0.y + tm[2] * xb0.z + tm[3] * xb0.w
           + tm[4] * xb1.x + tm[5] * xb1.y + tm[6] * xb1.z + tm[7] * xb1.w;
}

// ===========================================================================
// K4a: out[m][o] += sum_{c in 32-chunk} x[m][c] * base[c][o]   (atomic)
// grid (2 o-tiles, 64 c-split), block 256. Same template as k2s.
__global__ __launch_bounds__(256) void k4a(const float* __restrict__ x,
                                           const float* __restrict__ base,
                                           float* __restrict__ out) {
    const int t  = threadIdx.x;
    const int o4 = blockIdx.x * 256 + t;            // float4 col [0, 512)
    const int c0 = blockIdx.y * 32;
    __shared__ float xl[32][16];
    for (int i = t; i < 512; i += 256)
        xl[i >> 4][i & 15] = x[(i & 15) * DN + c0 + (i >> 4)];
    __syncthreads();

    float4 acc[16];
#pragma unroll
    for (int m = 0; m < 16; ++m) acc[m] = make_float4(0.f, 0.f, 0.f, 0.f);

    const float4* bp = (const float4*)base + (size_t)c0 * (DN / 4) + o4;
    float4 bbuf[8];
#pragma unroll
    for (int u = 0; u < 8; ++u) bbuf[u] = bp[(size_t)u * (DN / 4)];

    for (int co = 0; co < 4; ++co) {
#pragma unroll
        for (int u = 0; u < 8; ++u) {
            const int cc = co * 8 + u;
            const float4 bv = bbuf[u];
            const int nc = (cc + 8 < 32) ? cc + 8 : cc;   // uniform clamp
            bbuf[u] = bp[(size_t)nc * (DN / 4)];
            const float4 x0 = *(const float4*)&xl[cc][0];
            const float4 x1 = *(const float4*)&xl[cc][4];
            const float4 x2 = *(const float4*)&xl[cc][8];
            const float4 x3 = *(const float4*)&xl[cc][12];
#define A4(m, xs) do { acc[m].x = fmaf(xs, bv.x, acc[m].x); \
                       acc[m].y = fmaf(xs, bv.y, acc[m].y); \
                       acc[m].z = fmaf(xs, bv.z, acc[m].z); \
                       acc[m].w = fmaf(xs, bv.w, acc[m].w); } while (0)
            A4(0, x0.x);  A4(1, x0.y);  A4(2, x0.z);  A4(3, x0.w);
            A4(4, x1.x);  A4(5, x1.y);  A4(6, x1.z);  A4(7, x1.w);
            A4(8, x2.x);  A4(9, x2.y);  A4(10, x2.z); A4(11, x2.w);
            A4(12, x3.x); A4(13, x3.y); A4(14, x3.z); A4(15, x3.w);
#undef A4
        }
    }
#pragma unroll
    for (int m = 0; m < 16; ++m) {
        float* d = out + (size_t)m * DN + o4 * 4;
        atomicAdd(d + 0, acc[m].x); atomicAdd(d + 1, acc[m].y);
        atomicAdd(d + 2, acc[m].z); atomicAdd(d + 3, acc[m].w);
    }
}

// ===========================================================================
extern "C" void kernel_launch(void* const* d_in, const int* in_sizes, int n_in,
                              void* d_out, int out_size, void* d_ws, size_t ws_size,
                              hipStream_t stream) {
    const float* x    = (const float*)d_in[0];
    const float* ada  = (const float*)d_in[1];
    const float* base = (const float*)d_in[2];
    const float* w1   = (const float*)d_in[3];
    const float* b1   = (const float*)d_in[4];
    const float* w2   = (const float*)d_in[5];
    const float* b2   = (const float*)d_in[6];
    float* out = (float*)d_out;
    char* ws = (char*)d_ws;

    // ws layout (bytes): xw @0 (2,097,152) | h_pre @2,097,152 (65,536)
    //                    | h_t @2,162,688 (65,536) | t @2,228,224 (512)
    float* xw    = (float*)(ws);
    float* h_pre = (float*)(ws + 2097152);
    float* h_t   = (float*)(ws + 2162688);
    float* t     = (float*)(ws + 2228224);

    hipMemsetAsync(h_pre, 0, 65536, stream);     // k1a2 atomic accumulator

    xwinit<<<512,           256, 0, stream>>>(b2, xw);
    k1a2  <<<32,            256, 0, stream>>>(ada, w1, h_pre);
    k1bt  <<<64,            256, 0, stream>>>(h_pre, b1, h_t);
    k2s   <<<dim3(32, 32),  256, 0, stream>>>(h_t, w2, xw);
    k3    <<<128,           256, 0, stream>>>(x, xw, t);
    k5i   <<<128,           256, 0, stream>>>(x, xw, t, out);
    k4a   <<<dim3(2, 64),   256, 0, stream>>>(x, base, out);
}

// Round 6
// 108.950 us; speedup vs baseline: 3.4336x; 3.4336x over previous
//
#include <hip/hip_runtime.h>
#include <math.h>

#define BN 16
#define DN 2048
#define ADA 1024
#define INTER 1024
#define NW2 32768   // D*RANK*2
#define HALFN 16384

// ===========================================================================
// K1a: h_pre[m][j] += sum over k-chunk of ada[m][k]*w1[k][j]   (atomic k-split;
// 0.5M atomics total - measured tolerable in r1-r3)
__global__ void k1a(const float* __restrict__ ada, const float* __restrict__ w1,
                    float* __restrict__ h_pre) {
    const int j  = blockIdx.x * 256 + threadIdx.x;
    const int k0 = blockIdx.y * 32;
    __shared__ float a_lds[BN][32];
    for (int idx = threadIdx.x; idx < BN * 32; idx += 256) {
        int m = idx >> 5, kk = idx & 31;
        a_lds[m][kk] = ada[m * ADA + k0 + kk];
    }
    __syncthreads();
    float acc[BN];
#pragma unroll
    for (int m = 0; m < BN; ++m) acc[m] = 0.f;
    for (int kk = 0; kk < 32; ++kk) {
        float w = w1[(k0 + kk) * INTER + j];
#pragma unroll
        for (int m = 0; m < BN; ++m) acc[m] += a_lds[m][kk] * w;
    }
#pragma unroll
    for (int m = 0; m < BN; ++m) atomicAdd(&h_pre[m * INTER + j], acc[m]);
}

// ===========================================================================
// K1b-T: h_t[k][m] = gelu_exact(h_pre[m][k] + b1[k])   (transposed output)
__global__ void k1bt(const float* __restrict__ h_pre, const float* __restrict__ b1,
                     float* __restrict__ h_t) {
    int i = blockIdx.x * 256 + threadIdx.x;     // 16384 elements
    int m = i >> 10, j = i & (INTER - 1);
    float v = h_pre[i] + b1[j];
    float g = 0.5f * v * (1.f + erff(v * 0.70710678118654752f));
    h_t[j * BN + m] = g;
}

// ===========================================================================
// K2n: p2[ks][m][n] = sum_{k in 128-chunk} h_t[k][m] * w2[k][n]
// grid (64 n-tiles, 8 k-slices), block 512 = 4 ksubs x 128 threads.
// Thread owns a float4 of n (1 KB wave-loads); 8-deep rolling prefetch;
// h chunk staged in LDS (lgkmcnt path only, uniform broadcast reads);
// in-block LDS reduce across ksubs (NO atomics); 16 waves/CU.
__global__ __launch_bounds__(512, 4) void k2n(const float* __restrict__ h_t,
                                              const float* __restrict__ w2,
                                              float* __restrict__ p2) {
    const int tid  = threadIdx.x;
    const int ksub = tid >> 7;            // 0..3
    const int tn   = tid & 127;           // thread within ksub group
    const int kb0  = blockIdx.y * 128;    // block k-range (128 k)
    const int k0   = kb0 + ksub * 32;     // this ksub's 32-k range

    __shared__ float hl[128][16];         // 8 KB staged h_t chunk
    __shared__ float red[16][512];        // 32 KB cross-ksub reduce buffer

    // stage h_t[kb0 .. kb0+128)[*] : 2048 floats = 512 float4, 1 per thread
    ((float4*)hl)[tid] = ((const float4*)(h_t + kb0 * BN))[tid];
    __syncthreads();

    float4 acc[BN];
#pragma unroll
    for (int m = 0; m < BN; ++m) acc[m] = make_float4(0.f, 0.f, 0.f, 0.f);

    const float4* wp = (const float4*)w2 + (size_t)k0 * (NW2 / 4)
                     + blockIdx.x * 128 + tn;
    float4 wbuf[8];
#pragma unroll
    for (int u = 0; u < 8; ++u) wbuf[u] = wp[(size_t)u * (NW2 / 4)];

    for (int ko = 0; ko < 4; ++ko) {
#pragma unroll
        for (int u = 0; u < 8; ++u) {
            const int kk = ko * 8 + u;
            const float4 wv = wbuf[u];
            const int nk = (kk + 8 < 32) ? kk + 8 : kk;   // uniform clamp (L2-hot reload)
            wbuf[u] = wp[(size_t)nk * (NW2 / 4)];
            const float* hk = &hl[ksub * 32 + kk][0];
            const float4 h0 = *(const float4*)(hk + 0);
            const float4 h1 = *(const float4*)(hk + 4);
            const float4 h2 = *(const float4*)(hk + 8);
            const float4 h3 = *(const float4*)(hk + 12);
#define A2(m, hs) do { acc[m].x = fmaf(hs, wv.x, acc[m].x); \
                       acc[m].y = fmaf(hs, wv.y, acc[m].y); \
                       acc[m].z = fmaf(hs, wv.z, acc[m].z); \
                       acc[m].w = fmaf(hs, wv.w, acc[m].w); } while (0)
            A2(0, h0.x);  A2(1, h0.y);  A2(2, h0.z);  A2(3, h0.w);
            A2(4, h1.x);  A2(5, h1.y);  A2(6, h1.z);  A2(7, h1.w);
            A2(8, h2.x);  A2(9, h2.y);  A2(10, h2.z); A2(11, h2.w);
            A2(12, h3.x); A2(13, h3.y); A2(14, h3.z); A2(15, h3.w);
#undef A2
        }
    }

    // cross-ksub reduction in LDS (serialized adds, 4 barriers)
    if (ksub == 0) {
#pragma unroll
        for (int m = 0; m < BN; ++m) *(float4*)&red[m][tn * 4] = acc[m];
    }
    __syncthreads();
#pragma unroll
    for (int s = 1; s < 4; ++s) {
        if (ksub == s) {
#pragma unroll
            for (int m = 0; m < BN; ++m) {
                float4 r = *(float4*)&red[m][tn * 4];
                r.x += acc[m].x; r.y += acc[m].y; r.z += acc[m].z; r.w += acc[m].w;
                *(float4*)&red[m][tn * 4] = r;
            }
        }
        __syncthreads();
    }

    // write partial slice: 16 m x 512 n floats; thread writes 4 m at its col
    float* op = p2 + (size_t)blockIdx.y * (BN * NW2) + blockIdx.x * 512 + tn * 4;
#pragma unroll
    for (int q = 0; q < 4; ++q) {
        const int m = ksub + q * 4;
        *(float4*)(op + (size_t)m * NW2) = *(float4*)&red[m][tn * 4];
    }
}

// ===========================================================================
// K2r: xw[m][n] = b2[n] + sum_{ks<8} p2[ks][m][n]    (float4, fully coalesced)
__global__ void k2r(const float* __restrict__ p2, const float* __restrict__ b2,
                    float* __restrict__ xw) {
    const int i  = blockIdx.x * 256 + threadIdx.x;  // float4 idx over 131072
    const int n4 = i & (NW2 / 4 - 1);
    float4 s = ((const float4*)b2)[n4];
    const float4* p = (const float4*)p2 + i;
#pragma unroll
    for (int ks = 0; ks < 8; ++ks) {
        float4 v = p[(size_t)ks * (BN * NW2 / 4)];
        s.x += v.x; s.y += v.y; s.z += v.z; s.w += v.w;
    }
    ((float4*)xw)[i] = s;
}

// ===========================================================================
// K3: t[m][r] = sum_c x[m][c] * xw[m][c*8+r]   (x_a half)
__global__ void k3(const float* __restrict__ x, const float* __restrict__ xw,
                   float* __restrict__ t) {
    const int m = blockIdx.x >> 3, r = blockIdx.x & 7;
    float s = 0.f;
    for (int c = threadIdx.x; c < DN; c += 256)
        s += x[m * DN + c] * xw[(size_t)m * NW2 + c * 8 + r];
    __shared__ float red[256];
    red[threadIdx.x] = s;
    __syncthreads();
    for (int off = 128; off > 0; off >>= 1) {
        if (threadIdx.x < off) red[threadIdx.x] += red[threadIdx.x + off];
        __syncthreads();
    }
    if (threadIdx.x == 0) t[m * 8 + r] = red[0];
}

// ===========================================================================
// K4m: p4[cs][m][o] = sum_{c in 32-chunk} x[m][c] * base[c][o]
// grid (2, 64, 2), block 256. Thread owns float4 of o for 8 m; no LDS.
#define K4ACC(i, xv) do { acc[i].x = fmaf((xv), b.x, acc[i].x); \
                          acc[i].y = fmaf((xv), b.y, acc[i].y); \
                          acc[i].z = fmaf((xv), b.z, acc[i].z); \
                          acc[i].w = fmaf((xv), b.w, acc[i].w); } while (0)
__global__ __launch_bounds__(256) void k4m(const float* __restrict__ x,
                                           const float* __restrict__ base,
                                           float* __restrict__ p4) {
    const int o4 = blockIdx.x * 256 + threadIdx.x;   // [0, 512)
    const int c0 = blockIdx.y * 32;
    const int m0 = blockIdx.z * 8;
    float4 acc[8];
#pragma unroll
    for (int m = 0; m < 8; ++m) acc[m] = make_float4(0.f, 0.f, 0.f, 0.f);

    const float4* bp = (const float4*)base + (size_t)c0 * (DN / 4) + o4;
    float4 bbuf[8];
#pragma unroll
    for (int u = 0; u < 8; ++u) bbuf[u] = bp[(size_t)u * (DN / 4)];

    for (int cb = 0; cb < 32; cb += 8) {
#pragma unroll
        for (int u = 0; u < 8; ++u) {
            const int cc = cb + u;
            const float4 b = bbuf[u];
            const int cn = (cc + 8 < 32) ? (cc + 8) : cc;    // uniform clamp
            bbuf[u] = bp[(size_t)cn * (DN / 4)];
            const float x0 = x[(m0 + 0) * DN + c0 + cc];
            const float x1 = x[(m0 + 1) * DN + c0 + cc];
            const float x2 = x[(m0 + 2) * DN + c0 + cc];
            const float x3 = x[(m0 + 3) * DN + c0 + cc];
            const float x4 = x[(m0 + 4) * DN + c0 + cc];
            const float x5 = x[(m0 + 5) * DN + c0 + cc];
            const float x6 = x[(m0 + 6) * DN + c0 + cc];
            const float x7 = x[(m0 + 7) * DN + c0 + cc];
            K4ACC(0, x0); K4ACC(1, x1); K4ACC(2, x2); K4ACC(3, x3);
            K4ACC(4, x4); K4ACC(5, x5); K4ACC(6, x6); K4ACC(7, x7);
        }
    }
    float4* op = (float4*)p4 + (size_t)blockIdx.y * (BN * DN / 4)
               + (size_t)m0 * (DN / 4) + o4;
#pragma unroll
    for (int m = 0; m < 8; ++m) op[(size_t)m * (DN / 4)] = acc[m];
}

// ===========================================================================
// K5: out[m][o] = x[m][o] + sum_{cs<64} p4[cs][m][o] + sum_r t[m][r]*x_b[m][o][r]
__global__ void k5(const float* __restrict__ x, const float* __restrict__ p4,
                   const float* __restrict__ xw, const float* __restrict__ t,
                   float* __restrict__ out) {
    const int i = blockIdx.x * 256 + threadIdx.x;   // [0, 32768)
    const int m = i >> 11, o = i & (DN - 1);
    float s = x[i];
    const float* p = p4 + i;
#pragma unroll 8
    for (int ks = 0; ks < 64; ++ks) s += p[ks * (BN * DN)];
    const float4 xb0 = *(const float4*)(xw + (size_t)m * NW2 + HALFN + o * 8);
    const float4 xb1 = *(const float4*)(xw + (size_t)m * NW2 + HALFN + o * 8 + 4);
    const float* tm = t + m * 8;
    s += tm[0] * xb0.x + tm[1] * xb0.y + tm[2] * xb0.z + tm[3] * xb0.w
       + tm[4] * xb1.x + tm[5] * xb1.y + tm[6] * xb1.z + tm[7] * xb1.w;
    out[i] = s;
}

// ===========================================================================
extern "C" void kernel_launch(void* const* d_in, const int* in_sizes, int n_in,
                              void* d_out, int out_size, void* d_ws, size_t ws_size,
                              hipStream_t stream) {
    const float* x    = (const float*)d_in[0];
    const float* ada  = (const float*)d_in[1];
    const float* base = (const float*)d_in[2];
    const float* w1   = (const float*)d_in[3];
    const float* b1   = (const float*)d_in[4];
    const float* w2   = (const float*)d_in[5];
    const float* b2   = (const float*)d_in[6];
    float* out = (float*)d_out;
    char* ws = (char*)d_ws;

    // ws layout (bytes):
    //   p2    @ 0           (8 * 16*32768*4 = 16,777,216)
    //   xw    @ 16,777,216  (2,097,152)
    //   p4    @ 18,874,368  (64 * 16*2048*4 = 8,388,608)
    //   h_pre @ 27,262,976  (65,536)
    //   h_t   @ 27,328,512  (65,536)
    //   t     @ 27,394,048  (512)
    float* p2    = (float*)(ws);
    float* xw    = (float*)(ws + 16777216);
    float* p4    = (float*)(ws + 18874368);
    float* h_pre = (float*)(ws + 27262976);
    float* h_t   = (float*)(ws + 27328512);
    float* t     = (float*)(ws + 27394048);

    hipMemsetAsync(h_pre, 0, 65536, stream);   // k1a atomic accumulator only

    k1a <<<dim3(4, 32),    256, 0, stream>>>(ada, w1, h_pre);
    k1bt<<<64,             256, 0, stream>>>(h_pre, b1, h_t);
    k2n <<<dim3(64, 8),    512, 0, stream>>>(h_t, w2, p2);
    k4m <<<dim3(2, 64, 2), 256, 0, stream>>>(x, base, p4);
    k2r <<<512,            256, 0, stream>>>(p2, b2, xw);
    k3  <<<128,            256, 0, stream>>>(x, xw, t);
    k5  <<<128,            256, 0, stream>>>(x, p4, xw, t, out);
}

// Round 7
// 73.745 us; speedup vs baseline: 5.0728x; 1.4774x over previous
//
#include <hip/hip_runtime.h>
#include <math.h>

#define BN 16
#define DN 2048
#define ADA 1024
#define INTER 1024
#define NW2 32768   // D*RANK*2
#define HALFN 16384

// ===========================================================================
// K1a: h_pre[m][j] += sum over k-chunk of ada[m][k]*w1[k][j]   (atomic k-split;
// 0.5M atomics total - measured tolerable in r1-r3)
__global__ void k1a(const float* __restrict__ ada, const float* __restrict__ w1,
                    float* __restrict__ h_pre) {
    const int j  = blockIdx.x * 256 + threadIdx.x;
    const int k0 = blockIdx.y * 32;
    __shared__ float a_lds[BN][32];
    for (int idx = threadIdx.x; idx < BN * 32; idx += 256) {
        int m = idx >> 5, kk = idx & 31;
        a_lds[m][kk] = ada[m * ADA + k0 + kk];
    }
    __syncthreads();
    float acc[BN];
#pragma unroll
    for (int m = 0; m < BN; ++m) acc[m] = 0.f;
    for (int kk = 0; kk < 32; ++kk) {
        float w = w1[(k0 + kk) * INTER + j];
#pragma unroll
        for (int m = 0; m < BN; ++m) acc[m] += a_lds[m][kk] * w;
    }
#pragma unroll
    for (int m = 0; m < BN; ++m) atomicAdd(&h_pre[m * INTER + j], acc[m]);
}

// ===========================================================================
// K1b-T: h_t[k][m] = gelu_exact(h_pre[m][k] + b1[k])   (transposed output)
__global__ void k1bt(const float* __restrict__ h_pre, const float* __restrict__ b1,
                     float* __restrict__ h_t) {
    int i = blockIdx.x * 256 + threadIdx.x;     // 16384 elements
    int m = i >> 10, j = i & (INTER - 1);
    float v = h_pre[i] + b1[j];
    float g = 0.5f * v * (1.f + erff(v * 0.70710678118654752f));
    h_t[j * BN + m] = g;
}

// ===========================================================================
// K2n: p2[ks][m][n] = sum_{k in 128-chunk} h_t[k][m] * w2[k][n]
// grid (64 n-tiles, 8 k-slices), block 512 = 4 ksubs x 128 threads.
// Thread owns a float4 of n (1 KB wave-loads); 8-deep rolling prefetch;
// h chunk staged in LDS (lgkmcnt path only, uniform broadcast reads);
// in-block LDS reduce across ksubs (NO atomics).
// launch_bounds(512, 2): 128-VGPR cap -> acc[16]f4 (64) + wbuf[8]f4 (32)
// fit WITHOUT spilling (r6's (512,4) forced 64 VGPR -> 145 MB scratch traffic).
__global__ __launch_bounds__(512, 2) void k2n(const float* __restrict__ h_t,
                                              const float* __restrict__ w2,
                                              float* __restrict__ p2) {
    const int tid  = threadIdx.x;
    const int ksub = tid >> 7;            // 0..3
    const int tn   = tid & 127;           // thread within ksub group
    const int kb0  = blockIdx.y * 128;    // block k-range (128 k)
    const int k0   = kb0 + ksub * 32;     // this ksub's 32-k range

    __shared__ float hl[128][16];         // 8 KB staged h_t chunk
    __shared__ float red[16][512];        // 32 KB cross-ksub reduce buffer

    // stage h_t[kb0 .. kb0+128)[*] : 2048 floats = 512 float4, 1 per thread
    ((float4*)hl)[tid] = ((const float4*)(h_t + kb0 * BN))[tid];
    __syncthreads();

    float4 acc[BN];
#pragma unroll
    for (int m = 0; m < BN; ++m) acc[m] = make_float4(0.f, 0.f, 0.f, 0.f);

    const float4* wp = (const float4*)w2 + (size_t)k0 * (NW2 / 4)
                     + blockIdx.x * 128 + tn;
    float4 wbuf[8];
#pragma unroll
    for (int u = 0; u < 8; ++u) wbuf[u] = wp[(size_t)u * (NW2 / 4)];

    for (int ko = 0; ko < 4; ++ko) {
#pragma unroll
        for (int u = 0; u < 8; ++u) {
            const int kk = ko * 8 + u;
            const float4 wv = wbuf[u];
            const int nk = (kk + 8 < 32) ? kk + 8 : kk;   // uniform clamp (L2-hot reload)
            wbuf[u] = wp[(size_t)nk * (NW2 / 4)];
            const float* hk = &hl[ksub * 32 + kk][0];
            const float4 h0 = *(const float4*)(hk + 0);
            const float4 h1 = *(const float4*)(hk + 4);
            const float4 h2 = *(const float4*)(hk + 8);
            const float4 h3 = *(const float4*)(hk + 12);
#define A2(m, hs) do { acc[m].x = fmaf(hs, wv.x, acc[m].x); \
                       acc[m].y = fmaf(hs, wv.y, acc[m].y); \
                       acc[m].z = fmaf(hs, wv.z, acc[m].z); \
                       acc[m].w = fmaf(hs, wv.w, acc[m].w); } while (0)
            A2(0, h0.x);  A2(1, h0.y);  A2(2, h0.z);  A2(3, h0.w);
            A2(4, h1.x);  A2(5, h1.y);  A2(6, h1.z);  A2(7, h1.w);
            A2(8, h2.x);  A2(9, h2.y);  A2(10, h2.z); A2(11, h2.w);
            A2(12, h3.x); A2(13, h3.y); A2(14, h3.z); A2(15, h3.w);
#undef A2
        }
    }

    // cross-ksub reduction in LDS (serialized adds, 4 barriers)
    if (ksub == 0) {
#pragma unroll
        for (int m = 0; m < BN; ++m) *(float4*)&red[m][tn * 4] = acc[m];
    }
    __syncthreads();
#pragma unroll
    for (int s = 1; s < 4; ++s) {
        if (ksub == s) {
#pragma unroll
            for (int m = 0; m < BN; ++m) {
                float4 r = *(float4*)&red[m][tn * 4];
                r.x += acc[m].x; r.y += acc[m].y; r.z += acc[m].z; r.w += acc[m].w;
                *(float4*)&red[m][tn * 4] = r;
            }
        }
        __syncthreads();
    }

    // write partial slice: 16 m x 512 n floats; thread writes 4 m at its col
    float* op = p2 + (size_t)blockIdx.y * (BN * NW2) + blockIdx.x * 512 + tn * 4;
#pragma unroll
    for (int q = 0; q < 4; ++q) {
        const int m = ksub + q * 4;
        *(float4*)(op + (size_t)m * NW2) = *(float4*)&red[m][tn * 4];
    }
}

// ===========================================================================
// K2r: xw[m][n] = b2[n] + sum_{ks<8} p2[ks][m][n]    (float4, fully coalesced)
__global__ void k2r(const float* __restrict__ p2, const float* __restrict__ b2,
                    float* __restrict__ xw) {
    const int i  = blockIdx.x * 256 + threadIdx.x;  // float4 idx over 131072
    const int n4 = i & (NW2 / 4 - 1);
    float4 s = ((const float4*)b2)[n4];
    const float4* p = (const float4*)p2 + i;
#pragma unroll
    for (int ks = 0; ks < 8; ++ks) {
        float4 v = p[(size_t)ks * (BN * NW2 / 4)];
        s.x += v.x; s.y += v.y; s.z += v.z; s.w += v.w;
    }
    ((float4*)xw)[i] = s;
}

// ===========================================================================
// K3: t[m][r] = sum_c x[m][c] * xw[m][c*8+r]   (x_a half)
__global__ void k3(const float* __restrict__ x, const float* __restrict__ xw,
                   float* __restrict__ t) {
    const int m = blockIdx.x >> 3, r = blockIdx.x & 7;
    float s = 0.f;
    for (int c = threadIdx.x; c < DN; c += 256)
        s += x[m * DN + c] * xw[(size_t)m * NW2 + c * 8 + r];
    __shared__ float red[256];
    red[threadIdx.x] = s;
    __syncthreads();
    for (int off = 128; off > 0; off >>= 1) {
        if (threadIdx.x < off) red[threadIdx.x] += red[threadIdx.x + off];
        __syncthreads();
    }
    if (threadIdx.x == 0) t[m * 8 + r] = red[0];
}

// ===========================================================================
// K4m: p4[cs][m][o] = sum_{c in 32-chunk} x[m][c] * base[c][o]
// grid (2, 64, 2), block 256. Thread owns float4 of o for 8 m; no LDS.
#define K4ACC(i, xv) do { acc[i].x = fmaf((xv), b.x, acc[i].x); \
                          acc[i].y = fmaf((xv), b.y, acc[i].y); \
                          acc[i].z = fmaf((xv), b.z, acc[i].z); \
                          acc[i].w = fmaf((xv), b.w, acc[i].w); } while (0)
__global__ __launch_bounds__(256) void k4m(const float* __restrict__ x,
                                           const float* __restrict__ base,
                                           float* __restrict__ p4) {
    const int o4 = blockIdx.x * 256 + threadIdx.x;   // [0, 512)
    const int c0 = blockIdx.y * 32;
    const int m0 = blockIdx.z * 8;
    float4 acc[8];
#pragma unroll
    for (int m = 0; m < 8; ++m) acc[m] = make_float4(0.f, 0.f, 0.f, 0.f);

    const float4* bp = (const float4*)base + (size_t)c0 * (DN / 4) + o4;
    float4 bbuf[8];
#pragma unroll
    for (int u = 0; u < 8; ++u) bbuf[u] = bp[(size_t)u * (DN / 4)];

    for (int cb = 0; cb < 32; cb += 8) {
#pragma unroll
        for (int u = 0; u < 8; ++u) {
            const int cc = cb + u;
            const float4 b = bbuf[u];
            const int cn = (cc + 8 < 32) ? (cc + 8) : cc;    // uniform clamp
            bbuf[u] = bp[(size_t)cn * (DN / 4)];
            const float x0 = x[(m0 + 0) * DN + c0 + cc];
            const float x1 = x[(m0 + 1) * DN + c0 + cc];
            const float x2 = x[(m0 + 2) * DN + c0 + cc];
            const float x3 = x[(m0 + 3) * DN + c0 + cc];
            const float x4 = x[(m0 + 4) * DN + c0 + cc];
            const float x5 = x[(m0 + 5) * DN + c0 + cc];
            const float x6 = x[(m0 + 6) * DN + c0 + cc];
            const float x7 = x[(m0 + 7) * DN + c0 + cc];
            K4ACC(0, x0); K4ACC(1, x1); K4ACC(2, x2); K4ACC(3, x3);
            K4ACC(4, x4); K4ACC(5, x5); K4ACC(6, x6); K4ACC(7, x7);
        }
    }
    float4* op = (float4*)p4 + (size_t)blockIdx.y * (BN * DN / 4)
               + (size_t)m0 * (DN / 4) + o4;
#pragma unroll
    for (int m = 0; m < 8; ++m) op[(size_t)m * (DN / 4)] = acc[m];
}

// ===========================================================================
// K5: out[m][o] = x[m][o] + sum_{cs<64} p4[cs][m][o] + sum_r t[m][r]*x_b[m][o][r]
__global__ void k5(const float* __restrict__ x, const float* __restrict__ p4,
                   const float* __restrict__ xw, const float* __restrict__ t,
                   float* __restrict__ out) {
    const int i = blockIdx.x * 256 + threadIdx.x;   // [0, 32768)
    const int m = i >> 11, o = i & (DN - 1);
    float s = x[i];
    const float* p = p4 + i;
#pragma unroll 8
    for (int ks = 0; ks < 64; ++ks) s += p[ks * (BN * DN)];
    const float4 xb0 = *(const float4*)(xw + (size_t)m * NW2 + HALFN + o * 8);
    const float4 xb1 = *(const float4*)(xw + (size_t)m * NW2 + HALFN + o * 8 + 4);
    const float* tm = t + m * 8;
    s += tm[0] * xb0.x + tm[1] * xb0.y + tm[2] * xb0.z + tm[3] * xb0.w
       + tm[4] * xb1.x + tm[5] * xb1.y + tm[6] * xb1.z + tm[7] * xb1.w;
    out[i] = s;
}

// ===========================================================================
extern "C" void kernel_launch(void* const* d_in, const int* in_sizes, int n_in,
                              void* d_out, int out_size, void* d_ws, size_t ws_size,
                              hipStream_t stream) {
    const float* x    = (const float*)d_in[0];
    const float* ada  = (const float*)d_in[1];
    const float* base = (const float*)d_in[2];
    const float* w1   = (const float*)d_in[3];
    const float* b1   = (const float*)d_in[4];
    const float* w2   = (const float*)d_in[5];
    const float* b2   = (const float*)d_in[6];
    float* out = (float*)d_out;
    char* ws = (char*)d_ws;

    // ws layout (bytes):
    //   p2    @ 0           (8 * 16*32768*4 = 16,777,216)
    //   xw    @ 16,777,216  (2,097,152)
    //   p4    @ 18,874,368  (64 * 16*2048*4 = 8,388,608)
    //   h_pre @ 27,262,976  (65,536)
    //   h_t   @ 27,328,512  (65,536)
    //   t     @ 27,394,048  (512)
    float* p2    = (float*)(ws);
    float* xw    = (float*)(ws + 16777216);
    float* p4    = (float*)(ws + 18874368);
    float* h_pre = (float*)(ws + 27262976);
    float* h_t   = (float*)(ws + 27328512);
    float* t     = (float*)(ws + 27394048);

    hipMemsetAsync(h_pre, 0, 65536, stream);   // k1a atomic accumulator only

    k1a <<<dim3(4, 32),    256, 0, stream>>>(ada, w1, h_pre);
    k1bt<<<64,             256, 0, stream>>>(h_pre, b1, h_t);
    k2n <<<dim3(64, 8),    512, 0, stream>>>(h_t, w2, p2);
    k4m <<<dim3(2, 64, 2), 256, 0, stream>>>(x, base, p4);
    k2r <<<512,            256, 0, stream>>>(p2, b2, xw);
    k3  <<<128,            256, 0, stream>>>(x, xw, t);
    k5  <<<128,            256, 0, stream>>>(x, p4, xw, t, out);
}